// Round 5
// baseline (180.232 us; speedup 1.0000x reference)
//
#include <hip/hip_runtime.h>
#include <hip/hip_bf16.h>

typedef __attribute__((ext_vector_type(4))) float f32x4;
typedef __attribute__((ext_vector_type(8))) short bf16x8;
typedef unsigned short ushort_t;

#define T_LEN 8192
#define N_REFL 8187              // last valid phase index (phase arrays have 8188 elems)
#define XT_T 8224                // padded transposed length: 8 front zeros, data 8..8199, zeros to 8223
#define POSTRIDE 66              // u16 per phase row (boundary path only)
#define PH_U16 (80 * POSTRIDE)   // 5280 u16 per phase (boundary path only)
#define N_INT 4032               // interior wave-groups: 16 b * 2 g * 126 tiles
#define WS_XT_OFF 262144         // byte offset of xT in ws (wbf occupies first 212,992 B)

__device__ __forceinline__ ushort_t f2bf(float f) {
    union { float f; unsigned u; } a; a.f = f;
    unsigned r = a.u + 0x7FFF + ((a.u >> 16) & 1);
    return (ushort_t)(r >> 16);
}

union bf2u { __hip_bfloat162 h; unsigned u; ushort_t s[2]; };

__device__ __forceinline__ unsigned pack_bf2(float a, float b) {
    bf2u x; x.h = __float22bfloat162_rn(make_float2(a, b));  // v_cvt_pk_bf16_f32
    return x.u;
}
__device__ __forceinline__ float bflo(unsigned u) {
    union { unsigned u; float f; } x; x.u = u << 16; return x.f;
}
__device__ __forceinline__ float bfhi(unsigned u) {
    union { unsigned u; float f; } x; x.u = u & 0xffff0000u; return x.f;
}
__device__ __forceinline__ float qgelu(float d) {
    return __fdividef(d, 1.f + __expf(-1.702f * d));
}
__device__ __forceinline__ float rot_lane(float v, int byteIdx) {
    int r = __builtin_amdgcn_ds_bpermute(byteIdx, __builtin_bit_cast(int, v));
    return __builtin_bit_cast(float, r);
}

// ---------------------------------------------------------------------------
// Repack w (128, 64, 13) f32 -> wbf[tap][o][c] bf16
__global__ void convert_w_kernel(const float* __restrict__ w, ushort_t* __restrict__ wbf) {
    int idx = blockIdx.x * 256 + threadIdx.x;
    if (idx >= 128 * 64 * 13) return;
    int tap = idx % 13;
    int c   = (idx / 13) & 63;
    int o   = idx / (13 * 64);
    wbf[(tap * 128 + o) * 64 + c] = f2bf(w[idx]);
}

// ---------------------------------------------------------------------------
// Transpose x[b][c][t] f32 -> xT[b][t+8][c] bf16, with zero pads at rows 0..7 and 8200..8223.
__global__ __launch_bounds__(256)
void transpose_kernel(const float* __restrict__ x, ushort_t* __restrict__ xT) {
    __shared__ float ts[64 * 133 + 128];   // [t][c], stride 133 (conflict-free writes)
    const int b   = blockIdx.y;
    const int t0  = blockIdx.x * 64;
    const int tid = threadIdx.x;

    // read: 4 c-rows per 16-lane group, 256B contiguous per row per instr
    const int cq = tid >> 4;          // 0..15
    const int tl = (tid & 15) * 4;    // 0..60
    #pragma unroll
    for (int cc = 0; cc < 8; ++cc) {
        int c = cq + 16 * cc;
        float4 v = *(const float4*)(x + ((size_t)(b * 128 + c)) * T_LEN + t0 + tl);
        ts[(tl + 0) * 133 + c] = v.x;
        ts[(tl + 1) * 133 + c] = v.y;
        ts[(tl + 2) * 133 + c] = v.z;
        ts[(tl + 3) * 133 + c] = v.w;
    }
    __syncthreads();

    // write: row (t0+t), 32 channels per thread, fully coalesced 16B stores
    const int t    = tid >> 2;        // 0..63
    const int part = tid & 3;
    const float* rp = ts + t * 133 + part * 32;
    ushort_t* dst = xT + ((size_t)b * XT_T + 8 + t0 + t) * 128 + part * 32;
    #pragma unroll
    for (int v4 = 0; v4 < 4; ++v4) {
        uint4 pv;
        pv.x = pack_bf2(rp[8 * v4 + 0], rp[8 * v4 + 1]);
        pv.y = pack_bf2(rp[8 * v4 + 2], rp[8 * v4 + 3]);
        pv.z = pack_bf2(rp[8 * v4 + 4], rp[8 * v4 + 5]);
        pv.w = pack_bf2(rp[8 * v4 + 6], rp[8 * v4 + 7]);
        *(uint4*)(dst + 8 * v4) = pv;
    }

    // zero pads (disjoint regions, no sync needed)
    uint4 z; z.x = z.y = z.z = z.w = 0u;
    if (blockIdx.x == 0) {
        uint4* fp = (uint4*)(xT + (size_t)b * XT_T * 128);
        for (int i = tid; i < 128; i += 256) fp[i] = z;          // rows 0..7
    }
    if (blockIdx.x == 127) {
        uint4* bp = (uint4*)(xT + ((size_t)b * XT_T + 8200) * 128);
        for (int i = tid; i < 384; i += 256) bp[i] = z;          // rows 8200..8223
    }
}

// ---------------------------------------------------------------------------
// Main kernel: interior = barrier-free per-wave MFMA + in-register epilogue.
__global__ __launch_bounds__(256, 4)
void fused_trconv_kernel(const ushort_t* __restrict__ xT, const ushort_t* __restrict__ wbf,
                         const float* __restrict__ bias, float* __restrict__ out) {
    __shared__ ushort_t smem[3 * PH_U16];   // used by boundary blocks only (31,680 B)

    const int bx   = blockIdx.x;
    const int tid  = threadIdx.x;
    const int lane = tid & 63;
    const int wv   = tid >> 6;
    const int row  = lane & 15;
    const int kb   = lane >> 4;

    int tile, g, b;
    if (bx < N_INT) {
        int gb = bx / 126;
        tile = 1 + (bx - gb * 126);
        g = gb & 1;
        b = gb >> 1;
    } else {
        int idx = bx - N_INT;
        tile = (idx & 1) ? 127 : 0;
        g = (idx >> 1) & 1;
        b = idx >> 2;
    }

    const ushort_t* xbase = xT + ((size_t)b * XT_T + (size_t)tile * 64) * 128 + g * 64;
    const int wo = g * 64 + wv * 16 + row;

    f32x4 accA[5], accL0[5], accL1[5];
    #pragma unroll
    for (int q = 0; q < 5; ++q) {
        accA[q]  = (f32x4){0.f, 0.f, 0.f, 0.f};
        accL0[q] = (f32x4){0.f, 0.f, 0.f, 0.f};
        accL1[q] = (f32x4){0.f, 0.f, 0.f, 0.f};
    }

    #pragma unroll
    for (int u = 0; u < 5; ++u) {
        #pragma unroll
        for (int h = 0; h < 2; ++h) {
            bf16x8 wf0 = *(const bf16x8*)(wbf + ((3 * u + 0) * 128 + wo) * 64 + h * 32 + kb * 8);
            bf16x8 wf1 = {}, wf2 = {};
            if (u < 4) {
                wf1 = *(const bf16x8*)(wbf + ((3 * u + 2) * 128 + wo) * 64 + h * 32 + kb * 8);
                wf2 = *(const bf16x8*)(wbf + ((3 * u + 1) * 128 + wo) * 64 + h * 32 + kb * 8);
            }
            #pragma unroll
            for (int q = 0; q < 5; ++q) {
                const bf16x8 xa = *(const bf16x8*)(xbase + (size_t)(16 * q + row + u) * 128 + h * 32 + kb * 8);
                accA[q] = __builtin_amdgcn_mfma_f32_16x16x32_bf16(xa, wf0, accA[q], 0, 0, 0);
                if (u < 4) {
                    accL0[q] = __builtin_amdgcn_mfma_f32_16x16x32_bf16(xa, wf1, accL0[q], 0, 0, 0);
                    accL1[q] = __builtin_amdgcn_mfma_f32_16x16x32_bf16(xa, wf2, accL1[q], 0, 0, 0);
                }
            }
        }
    }
    const float bo = bias[wo];

    if (bx < N_INT) {
        // ================= interior: in-register epilogue (no LDS, no barriers) =================
        const int upIdx = ((lane + 16) & 63) << 2;
        const int dnIdx = ((lane + 48) & 63) << 2;

        float u0[6], u1[6], d2m[5], d3m[5], lu[6], lv[6];
        #pragma unroll
        for (int q = 0; q < 5; ++q) {
            u0[q]  = rot_lane(accA[q][0], upIdx);
            u1[q]  = rot_lane(accA[q][1], upIdx);
            d2m[q] = rot_lane(accA[q][2], dnIdx);
            d3m[q] = rot_lane(accA[q][3], dnIdx);
            lu[q]  = rot_lane(accL0[q][0], upIdx);
            lv[q]  = rot_lane(accL1[q][0], upIdx);
        }
        u0[5] = 0.f; u1[5] = 0.f; lu[5] = 0.f; lv[5] = 0.f;

        const bool kbLT3 = (kb < 3);
        const bool kbGT0 = (kb > 0);
        const float c7bo = 7.f * bo;
        float* outBase = out + ((size_t)(b * 128 + wo)) * T_LEN + (tile * 64 - 6 + 4 * kb);

        #pragma unroll
        for (int q = 0; q < 5; ++q) {
            #pragma unroll
            for (int r = 0; r < 4; ++r) {
                float A0 = accA[q][r];
                float Ap1 = (r < 3) ? accA[q][r + 1] : (kbLT3 ? u0[q] : u0[q + 1]);
                float Ap2 = (r == 0) ? accA[q][2]
                          : (r == 1) ? accA[q][3]
                          : (r == 2) ? (kbLT3 ? u0[q] : u0[q + 1])
                                     : (kbLT3 ? u1[q] : u1[q + 1]);
                float Am1 = (r > 0) ? accA[q][r - 1]
                                    : (kbGT0 ? d3m[q] : (q > 0 ? d3m[q - 1] : 0.f));
                float Am2 = (r == 2) ? accA[q][0]
                          : (r == 3) ? accA[q][1]
                          : (r == 1) ? (kbGT0 ? d3m[q] : (q > 0 ? d3m[q - 1] : 0.f))
                                     : (kbGT0 ? d2m[q] : (q > 0 ? d2m[q - 1] : 0.f));
                float L0a = accL0[q][r];
                float L0b = (r < 3) ? accL0[q][r + 1] : (kbLT3 ? lu[q] : lu[q + 1]);
                float L1a = accL1[q][r];
                float L1b = (r < 3) ? accL1[q][r + 1] : (kbLT3 ? lv[q] : lv[q + 1]);

                float um = fmaxf(fmaxf(fmaxf(Am2, Am1), fmaxf(Ap1, Ap2)), A0);
                float res = 2.f * A0 + um + c7bo + (L0b + L0a) + (L1b + L1a)
                          + qgelu(L0b - L0a) + qgelu(L1b - L1a);

                bool ok = true;
                if (q == 0) ok = (4 * kb + r) >= 6;
                if (q == 4) ok = (4 * kb + r) <= 5;
                if (ok) outBase[16 * q + r] = res;
            }
        }
    } else {
        // ================= boundary tiles (0 and 127): LDS phase path =================
        const int t0    = tile * 64;
        const int mbase = t0 - 8;

        #pragma unroll
        for (int q = 0; q < 5; ++q) {
            #pragma unroll
            for (int p = 0; p < 3; ++p) {
                const f32x4& a = (p == 0) ? accA[q] : (p == 1) ? accL0[q] : accL1[q];
                unsigned pa = pack_bf2(a[0] + bo, a[1] + bo);
                unsigned pb = pack_bf2(a[2] + bo, a[3] + bo);
                int base = p * PH_U16 + (16 * q + kb * 4) * POSTRIDE + wv * 16 + row;
                smem[base + 0 * POSTRIDE] = (ushort_t)(pa & 0xffff);
                smem[base + 1 * POSTRIDE] = (ushort_t)(pa >> 16);
                smem[base + 2 * POSTRIDE] = (ushort_t)(pb & 0xffff);
                smem[base + 3 * POSTRIDE] = (ushort_t)(pb >> 16);
            }
        }
        __syncthreads();

        const int tl = tid & 63;
        const int wq = tid >> 6;
        const int t  = t0 + tl;
        const ushort_t* phA  = smem;
        const ushort_t* phL0 = smem + PH_U16;
        const ushort_t* phL1 = smem + 2 * PH_U16;
        float* outp = out + ((size_t)b * 128 + (size_t)g * 64) * T_LEN + t;

        int  s5[5];
        bool in5[5];
        #pragma unroll
        for (int dt = 0; dt < 5; ++dt) {
            int tp = t + dt - 2;
            in5[dt] = ((unsigned)tp < (unsigned)T_LEN);
            int ix = tp - 2;
            ix = (ix < 0) ? -ix : ix;
            ix = (ix > N_REFL) ? (2 * N_REFL - ix) : ix;
            s5[dt] = ix - mbase;
        }
        const int sC = s5[2];
        for (int i = 0; i < 8; ++i) {
            int o = 2 * wq + 8 * i;
            unsigned av[5];
            #pragma unroll
            for (int dt = 0; dt < 5; ++dt)
                av[dt] = *(const unsigned*)(phA + s5[dt] * POSTRIDE + o);
            unsigned l0a = *(const unsigned*)(phL0 + (sC    ) * POSTRIDE + o);
            unsigned l0b = *(const unsigned*)(phL0 + (sC + 1) * POSTRIDE + o);
            unsigned l1a = *(const unsigned*)(phL1 + (sC    ) * POSTRIDE + o);
            unsigned l1b = *(const unsigned*)(phL1 + (sC + 1) * POSTRIDE + o);

            float xm_l = bflo(av[2]), xm_h = bfhi(av[2]);
            float um_l = -1e30f, um_h = -1e30f;
            #pragma unroll
            for (int dt = 0; dt < 5; ++dt) {
                um_l = fmaxf(um_l, in5[dt] ? bflo(av[dt]) : 0.f);
                um_h = fmaxf(um_h, in5[dt] ? bfhi(av[dt]) : 0.f);
            }
            float l0al = bflo(l0a), l0bl = bflo(l0b), l1al = bflo(l1a), l1bl = bflo(l1b);
            float l0ah = bfhi(l0a), l0bh = bfhi(l0b), l1ah = bfhi(l1a), l1bh = bfhi(l1b);

            float rl = 2.f * xm_l + um_l + (l0bl + l0al) + qgelu(l0bl - l0al)
                                         + (l1bl + l1al) + qgelu(l1bl - l1al);
            float rh = 2.f * xm_h + um_h + (l0bh + l0ah) + qgelu(l0bh - l0ah)
                                         + (l1bh + l1ah) + qgelu(l1bh - l1ah);
            outp[(size_t)(o    ) * T_LEN] = rl;
            outp[(size_t)(o + 1) * T_LEN] = rh;
        }
    }
}

// ---------------------------------------------------------------------------
// Fallback (R3 verbatim): single fused kernel with LDS staging, used if ws too small.
__global__ __launch_bounds__(256, 4)
void fused_trconv_r3(const float* __restrict__ x, const ushort_t* __restrict__ wbf,
                     const float* __restrict__ bias, float* __restrict__ out) {
    __shared__ ushort_t smem[3 * PH_U16];
    ushort_t* xs = smem;

    const int bx    = blockIdx.x;
    const int tile  = bx & 127;
    const int g     = (bx >> 7) & 1;
    const int b     = bx >> 8;
    const int t0    = tile * 64;
    const int mbase = t0 - 8;
    const int tid   = threadIdx.x;

    const float* xg = x + ((size_t)b * 128 + (size_t)g * 64) * T_LEN;
    for (int cid = tid; cid < 64 * 22; cid += 256) {
        int c  = cid & 63;
        int kc = cid >> 6;
        int s0 = kc * 4;
        int m0 = mbase + s0;
        const float* src = xg + (size_t)c * T_LEN + m0;
        float v0, v1, v2, v3;
        if (m0 >= 0 && m0 + 3 < T_LEN) {
            float4 v = *(const float4*)src;
            v0 = v.x; v1 = v.y; v2 = v.z; v3 = v.w;
        } else {
            v0 = (m0 + 0 >= 0 && m0 + 0 < T_LEN) ? src[0] : 0.f;
            v1 = (m0 + 1 >= 0 && m0 + 1 < T_LEN) ? src[1] : 0.f;
            v2 = (m0 + 2 >= 0 && m0 + 2 < T_LEN) ? src[2] : 0.f;
            v3 = (m0 + 3 >= 0 && m0 + 3 < T_LEN) ? src[3] : 0.f;
        }
        unsigned p01 = pack_bf2(v0, v1);
        unsigned p23 = pack_bf2(v2, v3);
        xs[(s0 + 0) * 64 + (c ^ (((s0 + 0) & 7) << 3))] = (ushort_t)(p01 & 0xffff);
        xs[(s0 + 1) * 64 + (c ^ (((s0 + 1) & 7) << 3))] = (ushort_t)(p01 >> 16);
        xs[(s0 + 2) * 64 + (c ^ (((s0 + 2) & 7) << 3))] = (ushort_t)(p23 & 0xffff);
        xs[(s0 + 3) * 64 + (c ^ (((s0 + 3) & 7) << 3))] = (ushort_t)(p23 >> 16);
    }
    __syncthreads();

    const int lane = tid & 63;
    const int wv   = tid >> 6;
    const int row  = lane & 15;
    const int kb   = lane >> 4;

    f32x4 accA[5], accL0[5], accL1[5];
    #pragma unroll
    for (int q = 0; q < 5; ++q) {
        accA[q]  = (f32x4){0.f, 0.f, 0.f, 0.f};
        accL0[q] = (f32x4){0.f, 0.f, 0.f, 0.f};
        accL1[q] = (f32x4){0.f, 0.f, 0.f, 0.f};
    }
    const int wo = g * 64 + wv * 16 + row;

    #pragma unroll
    for (int u = 0; u < 5; ++u) {
        #pragma unroll
        for (int h = 0; h < 2; ++h) {
            bf16x8 wf0 = *(const bf16x8*)(wbf + ((3 * u + 0) * 128 + wo) * 64 + h * 32 + kb * 8);
            bf16x8 wf1 = {}, wf2 = {};
            if (u < 4) {
                wf1 = *(const bf16x8*)(wbf + ((3 * u + 2) * 128 + wo) * 64 + h * 32 + kb * 8);
                wf2 = *(const bf16x8*)(wbf + ((3 * u + 1) * 128 + wo) * 64 + h * 32 + kb * 8);
            }
            #pragma unroll
            for (int q = 0; q < 5; ++q) {
                int s = 16 * q + row + u;
                const bf16x8 xa = *(const bf16x8*)(xs + s * 64 + ((h * 32 + kb * 8) ^ ((s & 7) << 3)));
                accA[q] = __builtin_amdgcn_mfma_f32_16x16x32_bf16(xa, wf0, accA[q], 0, 0, 0);
                if (u < 4) {
                    accL0[q] = __builtin_amdgcn_mfma_f32_16x16x32_bf16(xa, wf1, accL0[q], 0, 0, 0);
                    accL1[q] = __builtin_amdgcn_mfma_f32_16x16x32_bf16(xa, wf2, accL1[q], 0, 0, 0);
                }
            }
        }
    }
    const float bo = bias[wo];

    if (tile != 0 && tile != 127) {
        const int upIdx = ((lane + 16) & 63) << 2;
        const int dnIdx = ((lane + 48) & 63) << 2;

        float u0[6], u1[6], d2m[5], d3m[5], lu[6], lv[6];
        #pragma unroll
        for (int q = 0; q < 5; ++q) {
            u0[q]  = rot_lane(accA[q][0], upIdx);
            u1[q]  = rot_lane(accA[q][1], upIdx);
            d2m[q] = rot_lane(accA[q][2], dnIdx);
            d3m[q] = rot_lane(accA[q][3], dnIdx);
            lu[q]  = rot_lane(accL0[q][0], upIdx);
            lv[q]  = rot_lane(accL1[q][0], upIdx);
        }
        u0[5] = 0.f; u1[5] = 0.f; lu[5] = 0.f; lv[5] = 0.f;

        const bool kbLT3 = (kb < 3);
        const bool kbGT0 = (kb > 0);
        const float c7bo = 7.f * bo;
        float* outBase = out + ((size_t)(b * 128 + wo)) * T_LEN + (t0 - 6 + 4 * kb);

        #pragma unroll
        for (int q = 0; q < 5; ++q) {
            #pragma unroll
            for (int r = 0; r < 4; ++r) {
                float A0 = accA[q][r];
                float Ap1 = (r < 3) ? accA[q][r + 1] : (kbLT3 ? u0[q] : u0[q + 1]);
                float Ap2 = (r == 0) ? accA[q][2]
                          : (r == 1) ? accA[q][3]
                          : (r == 2) ? (kbLT3 ? u0[q] : u0[q + 1])
                                     : (kbLT3 ? u1[q] : u1[q + 1]);
                float Am1 = (r > 0) ? accA[q][r - 1]
                                    : (kbGT0 ? d3m[q] : (q > 0 ? d3m[q - 1] : 0.f));
                float Am2 = (r == 2) ? accA[q][0]
                          : (r == 3) ? accA[q][1]
                          : (r == 1) ? (kbGT0 ? d3m[q] : (q > 0 ? d3m[q - 1] : 0.f))
                                     : (kbGT0 ? d2m[q] : (q > 0 ? d2m[q - 1] : 0.f));
                float L0a = accL0[q][r];
                float L0b = (r < 3) ? accL0[q][r + 1] : (kbLT3 ? lu[q] : lu[q + 1]);
                float L1a = accL1[q][r];
                float L1b = (r < 3) ? accL1[q][r + 1] : (kbLT3 ? lv[q] : lv[q + 1]);

                float um = fmaxf(fmaxf(fmaxf(Am2, Am1), fmaxf(Ap1, Ap2)), A0);
                float res = 2.f * A0 + um + c7bo + (L0b + L0a) + (L1b + L1a)
                          + qgelu(L0b - L0a) + qgelu(L1b - L1a);

                bool ok = true;
                if (q == 0) ok = (4 * kb + r) >= 6;
                if (q == 4) ok = (4 * kb + r) <= 5;
                if (ok) outBase[16 * q + r] = res;
            }
        }
    } else {
        __syncthreads();
        #pragma unroll
        for (int q = 0; q < 5; ++q) {
            #pragma unroll
            for (int p = 0; p < 3; ++p) {
                const f32x4& a = (p == 0) ? accA[q] : (p == 1) ? accL0[q] : accL1[q];
                unsigned pa = pack_bf2(a[0] + bo, a[1] + bo);
                unsigned pb = pack_bf2(a[2] + bo, a[3] + bo);
                int base = p * PH_U16 + (16 * q + kb * 4) * POSTRIDE + wv * 16 + row;
                smem[base + 0 * POSTRIDE] = (ushort_t)(pa & 0xffff);
                smem[base + 1 * POSTRIDE] = (ushort_t)(pa >> 16);
                smem[base + 2 * POSTRIDE] = (ushort_t)(pb & 0xffff);
                smem[base + 3 * POSTRIDE] = (ushort_t)(pb >> 16);
            }
        }
        __syncthreads();

        const int tl = tid & 63;
        const int wq = tid >> 6;
        const int t  = t0 + tl;
        const ushort_t* phA  = smem;
        const ushort_t* phL0 = smem + PH_U16;
        const ushort_t* phL1 = smem + 2 * PH_U16;
        float* outp = out + ((size_t)b * 128 + (size_t)g * 64) * T_LEN + t;

        int  s5[5];
        bool in5[5];
        #pragma unroll
        for (int dt = 0; dt < 5; ++dt) {
            int tp = t + dt - 2;
            in5[dt] = ((unsigned)tp < (unsigned)T_LEN);
            int ix = tp - 2;
            ix = (ix < 0) ? -ix : ix;
            ix = (ix > N_REFL) ? (2 * N_REFL - ix) : ix;
            s5[dt] = ix - mbase;
        }
        const int sC = s5[2];
        for (int i = 0; i < 8; ++i) {
            int o = 2 * wq + 8 * i;
            unsigned av[5];
            #pragma unroll
            for (int dt = 0; dt < 5; ++dt)
                av[dt] = *(const unsigned*)(phA + s5[dt] * POSTRIDE + o);
            unsigned l0a = *(const unsigned*)(phL0 + (sC    ) * POSTRIDE + o);
            unsigned l0b = *(const unsigned*)(phL0 + (sC + 1) * POSTRIDE + o);
            unsigned l1a = *(const unsigned*)(phL1 + (sC    ) * POSTRIDE + o);
            unsigned l1b = *(const unsigned*)(phL1 + (sC + 1) * POSTRIDE + o);

            float xm_l = bflo(av[2]), xm_h = bfhi(av[2]);
            float um_l = -1e30f, um_h = -1e30f;
            #pragma unroll
            for (int dt = 0; dt < 5; ++dt) {
                um_l = fmaxf(um_l, in5[dt] ? bflo(av[dt]) : 0.f);
                um_h = fmaxf(um_h, in5[dt] ? bfhi(av[dt]) : 0.f);
            }
            float l0al = bflo(l0a), l0bl = bflo(l0b), l1al = bflo(l1a), l1bl = bflo(l1b);
            float l0ah = bfhi(l0a), l0bh = bfhi(l0b), l1ah = bfhi(l1a), l1bh = bfhi(l1b);

            float rl = 2.f * xm_l + um_l + (l0bl + l0al) + qgelu(l0bl - l0al)
                                         + (l1bl + l1al) + qgelu(l1bl - l1al);
            float rh = 2.f * xm_h + um_h + (l0bh + l0ah) + qgelu(l0bh - l0ah)
                                         + (l1bh + l1ah) + qgelu(l1bh - l1ah);
            outp[(size_t)(o    ) * T_LEN] = rl;
            outp[(size_t)(o + 1) * T_LEN] = rh;
        }
    }
}

extern "C" void kernel_launch(void* const* d_in, const int* in_sizes, int n_in,
                              void* d_out, int out_size, void* d_ws, size_t ws_size,
                              hipStream_t stream) {
    const float* x    = (const float*)d_in[0];
    const float* w    = (const float*)d_in[1];
    const float* bias = (const float*)d_in[2];
    float* out        = (float*)d_out;
    ushort_t* wbf     = (ushort_t*)d_ws;    // 13*128*64*2 = 212,992 B

    hipLaunchKernelGGL(convert_w_kernel, dim3(416), dim3(256), 0, stream, w, wbf);

    const size_t need = WS_XT_OFF + (size_t)16 * XT_T * 128 * 2;  // ~33.9 MB
    if (ws_size >= need) {
        ushort_t* xT = (ushort_t*)((char*)d_ws + WS_XT_OFF);
        hipLaunchKernelGGL(transpose_kernel, dim3(128, 16), dim3(256), 0, stream, x, xT);
        hipLaunchKernelGGL(fused_trconv_kernel, dim3(N_INT + 64), dim3(256), 0, stream,
                           xT, wbf, bias, out);
    } else {
        hipLaunchKernelGGL(fused_trconv_r3, dim3(16 * 2 * 128), dim3(256), 0, stream,
                           x, wbf, bias, out);
    }
}

// Round 6
// 120.995 us; speedup vs baseline: 1.4896x; 1.4896x over previous
//
#include <hip/hip_runtime.h>
#include <hip/hip_bf16.h>

typedef __attribute__((ext_vector_type(4))) float f32x4;
typedef __attribute__((ext_vector_type(8))) short bf16x8;
typedef unsigned short ushort_t;

#define T_LEN 8192
#define N_REFL 8187              // last valid phase index (phase arrays have 8188 elems)
#define XT_R 8224                // padded rows: 0..7 zero, 8..8199 = t+8, 8200..8223 zero
#define POSTRIDE 66              // u16 per phase row (boundary path only)
#define PH_U16 (80 * POSTRIDE)   // 5280 u16 per phase (boundary path only)
#define N_INT 4032               // interior blocks: 126 tiles * 2 g * 16 b
#define WS_XT_OFF 262144         // byte offset of xT in ws (wbf occupies first 212,992 B)

#define AS1(p) ((const __attribute__((address_space(1))) unsigned int*)(p))
#define AS3(p) ((__attribute__((address_space(3))) unsigned int*)(p))

__device__ __forceinline__ ushort_t f2bf(float f) {
    union { float f; unsigned u; } a; a.f = f;
    unsigned r = a.u + 0x7FFF + ((a.u >> 16) & 1);
    return (ushort_t)(r >> 16);
}

union bf2u { __hip_bfloat162 h; unsigned u; ushort_t s[2]; };

__device__ __forceinline__ unsigned pack_bf2(float a, float b) {
    bf2u x; x.h = __float22bfloat162_rn(make_float2(a, b));  // v_cvt_pk_bf16_f32
    return x.u;
}
__device__ __forceinline__ float bflo(unsigned u) {
    union { unsigned u; float f; } x; x.u = u << 16; return x.f;
}
__device__ __forceinline__ float bfhi(unsigned u) {
    union { unsigned u; float f; } x; x.u = u & 0xffff0000u; return x.f;
}
__device__ __forceinline__ float qgelu(float d) {
    return __fdividef(d, 1.f + __expf(-1.702f * d));
}
__device__ __forceinline__ float rot_lane(float v, int byteIdx) {
    int r = __builtin_amdgcn_ds_bpermute(byteIdx, __builtin_bit_cast(int, v));
    return __builtin_bit_cast(float, r);
}

// ---------------------------------------------------------------------------
// Repack w (128, 64, 13) f32 -> wbf[tap][o][c] bf16
__global__ void convert_w_kernel(const float* __restrict__ w, ushort_t* __restrict__ wbf) {
    int idx = blockIdx.x * 256 + threadIdx.x;
    if (idx >= 128 * 64 * 13) return;
    int tap = idx % 13;
    int c   = (idx / 13) & 63;
    int o   = idx / (13 * 64);
    wbf[(tap * 128 + o) * 64 + c] = f2bf(w[idx]);
}

// ---------------------------------------------------------------------------
// Transpose x[b][c][t] f32 -> xT[g*16+b][r][c ^ ((r&7)<<3)] bf16 (r = t+8),
// with zero rows 0..7 and 8200..8223. Coalesced on both sides.
__global__ __launch_bounds__(256)
void transpose_kernel(const float* __restrict__ x, ushort_t* __restrict__ xT) {
    __shared__ float ts[64 * 133];   // [t][128c], stride 133
    const int b   = blockIdx.y;
    const int t0  = blockIdx.x * 64;
    const int tid = threadIdx.x;

    const int cq = tid >> 4;          // 0..15
    const int tl = (tid & 15) * 4;    // 0..60
    #pragma unroll
    for (int cc = 0; cc < 8; ++cc) {
        int c = cq + 16 * cc;
        float4 v = *(const float4*)(x + ((size_t)(b * 128 + c)) * T_LEN + t0 + tl);
        ts[(tl + 0) * 133 + c] = v.x;
        ts[(tl + 1) * 133 + c] = v.y;
        ts[(tl + 2) * 133 + c] = v.z;
        ts[(tl + 3) * 133 + c] = v.w;
    }
    __syncthreads();

    #pragma unroll
    for (int it = 0; it < 4; ++it) {
        int wid   = tid + 256 * it;      // 0..1023 = 2g * 64t * 8chunk
        int g     = wid >> 9;
        int rem   = wid & 511;
        int t     = rem >> 3;
        int chunk = rem & 7;
        int r     = t0 + t + 8;
        const float* rp = ts + t * 133 + g * 64 + chunk * 8;
        uint4 pv;
        pv.x = pack_bf2(rp[0], rp[1]);
        pv.y = pack_bf2(rp[2], rp[3]);
        pv.z = pack_bf2(rp[4], rp[5]);
        pv.w = pack_bf2(rp[6], rp[7]);
        int swz = chunk ^ (r & 7);
        *(uint4*)(xT + ((size_t)(g * 16 + b) * XT_R + r) * 64 + swz * 8) = pv;
    }

    uint4 z; z.x = z.y = z.z = z.w = 0u;
    if (blockIdx.x == 0) {
        for (int i = tid; i < 128; i += 256) {          // 2g * 8r * 8chunk
            int g = i >> 6, j = i & 63;
            int r = j >> 3, chunk = j & 7;
            *(uint4*)(xT + ((size_t)(g * 16 + b) * XT_R + r) * 64 + chunk * 8) = z;
        }
    }
    if (blockIdx.x == 127) {
        for (int i = tid; i < 384; i += 256) {          // 2g * 24r * 8chunk
            int g = i / 192, j = i % 192;
            int r = 8200 + (j >> 3), chunk = j & 7;
            *(uint4*)(xT + ((size_t)(g * 16 + b) * XT_R + r) * 64 + chunk * 8) = z;
        }
    }
}

// ---------------------------------------------------------------------------
// Interior kernel: global_load_lds stage (swizzle baked in xT) -> MFMA -> reg epilogue.
__global__ __launch_bounds__(256, 4)
void fused_int_kernel(const ushort_t* __restrict__ xT, const ushort_t* __restrict__ wbf,
                      const float* __restrict__ bias, float* __restrict__ out) {
    __shared__ ushort_t xs[88 * 64];    // 11,264 B

    const int bx   = blockIdx.x;
    const int tid  = threadIdx.x;
    const int lane = tid & 63;
    const int wv   = tid >> 6;
    const int row  = lane & 15;
    const int kb   = lane >> 4;

    const int gb   = bx / 126;
    const int tile = 1 + (bx - gb * 126);
    const int g    = gb & 1;
    const int b    = gb >> 1;

    // stage rows [64*tile, 64*tile+88) of plane (g,b): 11 x 1KB direct HBM->LDS
    {
        const char* gsrc = (const char*)(xT + ((size_t)(g * 16 + b) * XT_R + (size_t)tile * 64) * 64);
        for (int ch = wv; ch < 11; ch += 4) {
            __builtin_amdgcn_global_load_lds(AS1(gsrc + ch * 1024 + lane * 16),
                                             AS3((char*)xs + ch * 1024), 16, 0, 0);
        }
    }
    const int wo = g * 64 + wv * 16 + row;
    const float bo = bias[wo];
    __syncthreads();

    f32x4 accA[5], accL0[5], accL1[5];
    #pragma unroll
    for (int q = 0; q < 5; ++q) {
        accA[q]  = (f32x4){0.f, 0.f, 0.f, 0.f};
        accL0[q] = (f32x4){0.f, 0.f, 0.f, 0.f};
        accL1[q] = (f32x4){0.f, 0.f, 0.f, 0.f};
    }

    #pragma unroll
    for (int u = 0; u < 5; ++u) {
        #pragma unroll
        for (int h = 0; h < 2; ++h) {
            bf16x8 wf0 = *(const bf16x8*)(wbf + ((3 * u + 0) * 128 + wo) * 64 + h * 32 + kb * 8);
            bf16x8 wf1 = {}, wf2 = {};
            if (u < 4) {
                wf1 = *(const bf16x8*)(wbf + ((3 * u + 2) * 128 + wo) * 64 + h * 32 + kb * 8);
                wf2 = *(const bf16x8*)(wbf + ((3 * u + 1) * 128 + wo) * 64 + h * 32 + kb * 8);
            }
            #pragma unroll
            for (int q = 0; q < 5; ++q) {
                int s = 16 * q + row + u;
                const bf16x8 xa = *(const bf16x8*)(xs + s * 64 + ((h * 32 + kb * 8) ^ ((s & 7) << 3)));
                accA[q] = __builtin_amdgcn_mfma_f32_16x16x32_bf16(xa, wf0, accA[q], 0, 0, 0);
                if (u < 4) {
                    accL0[q] = __builtin_amdgcn_mfma_f32_16x16x32_bf16(xa, wf1, accL0[q], 0, 0, 0);
                    accL1[q] = __builtin_amdgcn_mfma_f32_16x16x32_bf16(xa, wf2, accL1[q], 0, 0, 0);
                }
            }
        }
    }

    // ---- in-register epilogue (no LDS, no barriers) ----
    const int upIdx = ((lane + 16) & 63) << 2;
    const int dnIdx = ((lane + 48) & 63) << 2;

    float u0[6], u1[6], d2m[5], d3m[5], lu[6], lv[6];
    #pragma unroll
    for (int q = 0; q < 5; ++q) {
        u0[q]  = rot_lane(accA[q][0], upIdx);
        u1[q]  = rot_lane(accA[q][1], upIdx);
        d2m[q] = rot_lane(accA[q][2], dnIdx);
        d3m[q] = rot_lane(accA[q][3], dnIdx);
        lu[q]  = rot_lane(accL0[q][0], upIdx);
        lv[q]  = rot_lane(accL1[q][0], upIdx);
    }
    u0[5] = 0.f; u1[5] = 0.f; lu[5] = 0.f; lv[5] = 0.f;

    const bool kbLT3 = (kb < 3);
    const bool kbGT0 = (kb > 0);
    const float c7bo = 7.f * bo;
    float* outBase = out + ((size_t)(b * 128 + wo)) * T_LEN + (tile * 64 - 6 + 4 * kb);

    #pragma unroll
    for (int q = 0; q < 5; ++q) {
        #pragma unroll
        for (int r = 0; r < 4; ++r) {
            float A0 = accA[q][r];
            float Ap1 = (r < 3) ? accA[q][r + 1] : (kbLT3 ? u0[q] : u0[q + 1]);
            float Ap2 = (r == 0) ? accA[q][2]
                      : (r == 1) ? accA[q][3]
                      : (r == 2) ? (kbLT3 ? u0[q] : u0[q + 1])
                                 : (kbLT3 ? u1[q] : u1[q + 1]);
            float Am1 = (r > 0) ? accA[q][r - 1]
                                : (kbGT0 ? d3m[q] : (q > 0 ? d3m[q - 1] : 0.f));
            float Am2 = (r == 2) ? accA[q][0]
                      : (r == 3) ? accA[q][1]
                      : (r == 1) ? (kbGT0 ? d3m[q] : (q > 0 ? d3m[q - 1] : 0.f))
                                 : (kbGT0 ? d2m[q] : (q > 0 ? d2m[q - 1] : 0.f));
            float L0a = accL0[q][r];
            float L0b = (r < 3) ? accL0[q][r + 1] : (kbLT3 ? lu[q] : lu[q + 1]);
            float L1a = accL1[q][r];
            float L1b = (r < 3) ? accL1[q][r + 1] : (kbLT3 ? lv[q] : lv[q + 1]);

            float um = fmaxf(fmaxf(fmaxf(Am2, Am1), fmaxf(Ap1, Ap2)), A0);
            float res = 2.f * A0 + um + c7bo + (L0b + L0a) + (L1b + L1a)
                      + qgelu(L0b - L0a) + qgelu(L1b - L1a);

            bool ok = true;
            if (q == 0) ok = (4 * kb + r) >= 6;
            if (q == 4) ok = (4 * kb + r) <= 5;
            if (ok) outBase[16 * q + r] = res;
        }
    }
}

// ---------------------------------------------------------------------------
// Boundary kernel (tiles 0 and 127, 64 blocks): LDS phase path, fed from xT pads.
__global__ __launch_bounds__(256, 4)
void fused_bnd_kernel(const ushort_t* __restrict__ xT, const ushort_t* __restrict__ wbf,
                      const float* __restrict__ bias, float* __restrict__ out) {
    __shared__ ushort_t smem[3 * PH_U16];   // 31,680 B; xs aliases the front
    ushort_t* xs = smem;

    const int idx  = blockIdx.x;
    const int tid  = threadIdx.x;
    const int lane = tid & 63;
    const int wv   = tid >> 6;
    const int row  = lane & 15;
    const int kb   = lane >> 4;

    const int tile = (idx & 1) ? 127 : 0;
    const int g    = (idx >> 1) & 1;
    const int b    = idx >> 2;
    const int t0    = tile * 64;
    const int mbase = t0 - 8;

    {
        const char* gsrc = (const char*)(xT + ((size_t)(g * 16 + b) * XT_R + (size_t)tile * 64) * 64);
        for (int ch = wv; ch < 11; ch += 4) {
            __builtin_amdgcn_global_load_lds(AS1(gsrc + ch * 1024 + lane * 16),
                                             AS3((char*)xs + ch * 1024), 16, 0, 0);
        }
    }
    const int wo = g * 64 + wv * 16 + row;
    const float bo = bias[wo];
    __syncthreads();

    f32x4 accA[5], accL0[5], accL1[5];
    #pragma unroll
    for (int q = 0; q < 5; ++q) {
        accA[q]  = (f32x4){0.f, 0.f, 0.f, 0.f};
        accL0[q] = (f32x4){0.f, 0.f, 0.f, 0.f};
        accL1[q] = (f32x4){0.f, 0.f, 0.f, 0.f};
    }

    #pragma unroll
    for (int u = 0; u < 5; ++u) {
        #pragma unroll
        for (int h = 0; h < 2; ++h) {
            bf16x8 wf0 = *(const bf16x8*)(wbf + ((3 * u + 0) * 128 + wo) * 64 + h * 32 + kb * 8);
            bf16x8 wf1 = {}, wf2 = {};
            if (u < 4) {
                wf1 = *(const bf16x8*)(wbf + ((3 * u + 2) * 128 + wo) * 64 + h * 32 + kb * 8);
                wf2 = *(const bf16x8*)(wbf + ((3 * u + 1) * 128 + wo) * 64 + h * 32 + kb * 8);
            }
            #pragma unroll
            for (int q = 0; q < 5; ++q) {
                int s = 16 * q + row + u;
                const bf16x8 xa = *(const bf16x8*)(xs + s * 64 + ((h * 32 + kb * 8) ^ ((s & 7) << 3)));
                accA[q] = __builtin_amdgcn_mfma_f32_16x16x32_bf16(xa, wf0, accA[q], 0, 0, 0);
                if (u < 4) {
                    accL0[q] = __builtin_amdgcn_mfma_f32_16x16x32_bf16(xa, wf1, accL0[q], 0, 0, 0);
                    accL1[q] = __builtin_amdgcn_mfma_f32_16x16x32_bf16(xa, wf2, accL1[q], 0, 0, 0);
                }
            }
        }
    }
    __syncthreads();   // done reading xs; safe to overwrite with phases

    #pragma unroll
    for (int q = 0; q < 5; ++q) {
        #pragma unroll
        for (int p = 0; p < 3; ++p) {
            const f32x4& a = (p == 0) ? accA[q] : (p == 1) ? accL0[q] : accL1[q];
            unsigned pa = pack_bf2(a[0] + bo, a[1] + bo);
            unsigned pb = pack_bf2(a[2] + bo, a[3] + bo);
            int base = p * PH_U16 + (16 * q + kb * 4) * POSTRIDE + wv * 16 + row;
            smem[base + 0 * POSTRIDE] = (ushort_t)(pa & 0xffff);
            smem[base + 1 * POSTRIDE] = (ushort_t)(pa >> 16);
            smem[base + 2 * POSTRIDE] = (ushort_t)(pb & 0xffff);
            smem[base + 3 * POSTRIDE] = (ushort_t)(pb >> 16);
        }
    }
    __syncthreads();

    const int tl = tid & 63;
    const int wq = tid >> 6;
    const int t  = t0 + tl;
    const ushort_t* phA  = smem;
    const ushort_t* phL0 = smem + PH_U16;
    const ushort_t* phL1 = smem + 2 * PH_U16;
    float* outp = out + ((size_t)b * 128 + (size_t)g * 64) * T_LEN + t;

    int  s5[5];
    bool in5[5];
    #pragma unroll
    for (int dt = 0; dt < 5; ++dt) {
        int tp = t + dt - 2;
        in5[dt] = ((unsigned)tp < (unsigned)T_LEN);
        int ix = tp - 2;
        ix = (ix < 0) ? -ix : ix;
        ix = (ix > N_REFL) ? (2 * N_REFL - ix) : ix;
        s5[dt] = ix - mbase;
    }
    const int sC = s5[2];
    for (int i = 0; i < 8; ++i) {
        int o = 2 * wq + 8 * i;
        unsigned av[5];
        #pragma unroll
        for (int dt = 0; dt < 5; ++dt)
            av[dt] = *(const unsigned*)(phA + s5[dt] * POSTRIDE + o);
        unsigned l0a = *(const unsigned*)(phL0 + (sC    ) * POSTRIDE + o);
        unsigned l0b = *(const unsigned*)(phL0 + (sC + 1) * POSTRIDE + o);
        unsigned l1a = *(const unsigned*)(phL1 + (sC    ) * POSTRIDE + o);
        unsigned l1b = *(const unsigned*)(phL1 + (sC + 1) * POSTRIDE + o);

        float xm_l = bflo(av[2]), xm_h = bfhi(av[2]);
        float um_l = -1e30f, um_h = -1e30f;
        #pragma unroll
        for (int dt = 0; dt < 5; ++dt) {
            um_l = fmaxf(um_l, in5[dt] ? bflo(av[dt]) : 0.f);
            um_h = fmaxf(um_h, in5[dt] ? bfhi(av[dt]) : 0.f);
        }
        float l0al = bflo(l0a), l0bl = bflo(l0b), l1al = bflo(l1a), l1bl = bflo(l1b);
        float l0ah = bfhi(l0a), l0bh = bfhi(l0b), l1ah = bfhi(l1a), l1bh = bfhi(l1b);

        float rl = 2.f * xm_l + um_l + (l0bl + l0al) + qgelu(l0bl - l0al)
                                     + (l1bl + l1al) + qgelu(l1bl - l1al);
        float rh = 2.f * xm_h + um_h + (l0bh + l0ah) + qgelu(l0bh - l0ah)
                                     + (l1bh + l1ah) + qgelu(l1bh - l1ah);
        outp[(size_t)(o    ) * T_LEN] = rl;
        outp[(size_t)(o + 1) * T_LEN] = rh;
    }
}

// ---------------------------------------------------------------------------
// Fallback (R3 verbatim): single fused kernel with LDS staging, used if ws too small.
__global__ __launch_bounds__(256, 4)
void fused_trconv_r3(const float* __restrict__ x, const ushort_t* __restrict__ wbf,
                     const float* __restrict__ bias, float* __restrict__ out) {
    __shared__ ushort_t smem[3 * PH_U16];
    ushort_t* xs = smem;

    const int bx    = blockIdx.x;
    const int tile  = bx & 127;
    const int g     = (bx >> 7) & 1;
    const int b     = bx >> 8;
    const int t0    = tile * 64;
    const int mbase = t0 - 8;
    const int tid   = threadIdx.x;

    const float* xg = x + ((size_t)b * 128 + (size_t)g * 64) * T_LEN;
    for (int cid = tid; cid < 64 * 22; cid += 256) {
        int c  = cid & 63;
        int kc = cid >> 6;
        int s0 = kc * 4;
        int m0 = mbase + s0;
        const float* src = xg + (size_t)c * T_LEN + m0;
        float v0, v1, v2, v3;
        if (m0 >= 0 && m0 + 3 < T_LEN) {
            float4 v = *(const float4*)src;
            v0 = v.x; v1 = v.y; v2 = v.z; v3 = v.w;
        } else {
            v0 = (m0 + 0 >= 0 && m0 + 0 < T_LEN) ? src[0] : 0.f;
            v1 = (m0 + 1 >= 0 && m0 + 1 < T_LEN) ? src[1] : 0.f;
            v2 = (m0 + 2 >= 0 && m0 + 2 < T_LEN) ? src[2] : 0.f;
            v3 = (m0 + 3 >= 0 && m0 + 3 < T_LEN) ? src[3] : 0.f;
        }
        unsigned p01 = pack_bf2(v0, v1);
        unsigned p23 = pack_bf2(v2, v3);
        xs[(s0 + 0) * 64 + (c ^ (((s0 + 0) & 7) << 3))] = (ushort_t)(p01 & 0xffff);
        xs[(s0 + 1) * 64 + (c ^ (((s0 + 1) & 7) << 3))] = (ushort_t)(p01 >> 16);
        xs[(s0 + 2) * 64 + (c ^ (((s0 + 2) & 7) << 3))] = (ushort_t)(p23 & 0xffff);
        xs[(s0 + 3) * 64 + (c ^ (((s0 + 3) & 7) << 3))] = (ushort_t)(p23 >> 16);
    }
    __syncthreads();

    const int lane = tid & 63;
    const int wv   = tid >> 6;
    const int row  = lane & 15;
    const int kb   = lane >> 4;

    f32x4 accA[5], accL0[5], accL1[5];
    #pragma unroll
    for (int q = 0; q < 5; ++q) {
        accA[q]  = (f32x4){0.f, 0.f, 0.f, 0.f};
        accL0[q] = (f32x4){0.f, 0.f, 0.f, 0.f};
        accL1[q] = (f32x4){0.f, 0.f, 0.f, 0.f};
    }
    const int wo = g * 64 + wv * 16 + row;

    #pragma unroll
    for (int u = 0; u < 5; ++u) {
        #pragma unroll
        for (int h = 0; h < 2; ++h) {
            bf16x8 wf0 = *(const bf16x8*)(wbf + ((3 * u + 0) * 128 + wo) * 64 + h * 32 + kb * 8);
            bf16x8 wf1 = {}, wf2 = {};
            if (u < 4) {
                wf1 = *(const bf16x8*)(wbf + ((3 * u + 2) * 128 + wo) * 64 + h * 32 + kb * 8);
                wf2 = *(const bf16x8*)(wbf + ((3 * u + 1) * 128 + wo) * 64 + h * 32 + kb * 8);
            }
            #pragma unroll
            for (int q = 0; q < 5; ++q) {
                int s = 16 * q + row + u;
                const bf16x8 xa = *(const bf16x8*)(xs + s * 64 + ((h * 32 + kb * 8) ^ ((s & 7) << 3)));
                accA[q] = __builtin_amdgcn_mfma_f32_16x16x32_bf16(xa, wf0, accA[q], 0, 0, 0);
                if (u < 4) {
                    accL0[q] = __builtin_amdgcn_mfma_f32_16x16x32_bf16(xa, wf1, accL0[q], 0, 0, 0);
                    accL1[q] = __builtin_amdgcn_mfma_f32_16x16x32_bf16(xa, wf2, accL1[q], 0, 0, 0);
                }
            }
        }
    }
    const float bo = bias[wo];

    if (tile != 0 && tile != 127) {
        const int upIdx = ((lane + 16) & 63) << 2;
        const int dnIdx = ((lane + 48) & 63) << 2;

        float u0[6], u1[6], d2m[5], d3m[5], lu[6], lv[6];
        #pragma unroll
        for (int q = 0; q < 5; ++q) {
            u0[q]  = rot_lane(accA[q][0], upIdx);
            u1[q]  = rot_lane(accA[q][1], upIdx);
            d2m[q] = rot_lane(accA[q][2], dnIdx);
            d3m[q] = rot_lane(accA[q][3], dnIdx);
            lu[q]  = rot_lane(accL0[q][0], upIdx);
            lv[q]  = rot_lane(accL1[q][0], upIdx);
        }
        u0[5] = 0.f; u1[5] = 0.f; lu[5] = 0.f; lv[5] = 0.f;

        const bool kbLT3 = (kb < 3);
        const bool kbGT0 = (kb > 0);
        const float c7bo = 7.f * bo;
        float* outBase = out + ((size_t)(b * 128 + wo)) * T_LEN + (t0 - 6 + 4 * kb);

        #pragma unroll
        for (int q = 0; q < 5; ++q) {
            #pragma unroll
            for (int r = 0; r < 4; ++r) {
                float A0 = accA[q][r];
                float Ap1 = (r < 3) ? accA[q][r + 1] : (kbLT3 ? u0[q] : u0[q + 1]);
                float Ap2 = (r == 0) ? accA[q][2]
                          : (r == 1) ? accA[q][3]
                          : (r == 2) ? (kbLT3 ? u0[q] : u0[q + 1])
                                     : (kbLT3 ? u1[q] : u1[q + 1]);
                float Am1 = (r > 0) ? accA[q][r - 1]
                                    : (kbGT0 ? d3m[q] : (q > 0 ? d3m[q - 1] : 0.f));
                float Am2 = (r == 2) ? accA[q][0]
                          : (r == 3) ? accA[q][1]
                          : (r == 1) ? (kbGT0 ? d3m[q] : (q > 0 ? d3m[q - 1] : 0.f))
                                     : (kbGT0 ? d2m[q] : (q > 0 ? d2m[q - 1] : 0.f));
                float L0a = accL0[q][r];
                float L0b = (r < 3) ? accL0[q][r + 1] : (kbLT3 ? lu[q] : lu[q + 1]);
                float L1a = accL1[q][r];
                float L1b = (r < 3) ? accL1[q][r + 1] : (kbLT3 ? lv[q] : lv[q + 1]);

                float um = fmaxf(fmaxf(fmaxf(Am2, Am1), fmaxf(Ap1, Ap2)), A0);
                float res = 2.f * A0 + um + c7bo + (L0b + L0a) + (L1b + L1a)
                          + qgelu(L0b - L0a) + qgelu(L1b - L1a);

                bool ok = true;
                if (q == 0) ok = (4 * kb + r) >= 6;
                if (q == 4) ok = (4 * kb + r) <= 5;
                if (ok) outBase[16 * q + r] = res;
            }
        }
    } else {
        __syncthreads();
        #pragma unroll
        for (int q = 0; q < 5; ++q) {
            #pragma unroll
            for (int p = 0; p < 3; ++p) {
                const f32x4& a = (p == 0) ? accA[q] : (p == 1) ? accL0[q] : accL1[q];
                unsigned pa = pack_bf2(a[0] + bo, a[1] + bo);
                unsigned pb = pack_bf2(a[2] + bo, a[3] + bo);
                int base = p * PH_U16 + (16 * q + kb * 4) * POSTRIDE + wv * 16 + row;
                smem[base + 0 * POSTRIDE] = (ushort_t)(pa & 0xffff);
                smem[base + 1 * POSTRIDE] = (ushort_t)(pa >> 16);
                smem[base + 2 * POSTRIDE] = (ushort_t)(pb & 0xffff);
                smem[base + 3 * POSTRIDE] = (ushort_t)(pb >> 16);
            }
        }
        __syncthreads();

        const int tl = tid & 63;
        const int wq = tid >> 6;
        const int t  = t0 + tl;
        const ushort_t* phA  = smem;
        const ushort_t* phL0 = smem + PH_U16;
        const ushort_t* phL1 = smem + 2 * PH_U16;
        float* outp = out + ((size_t)b * 128 + (size_t)g * 64) * T_LEN + t;

        int  s5[5];
        bool in5[5];
        #pragma unroll
        for (int dt = 0; dt < 5; ++dt) {
            int tp = t + dt - 2;
            in5[dt] = ((unsigned)tp < (unsigned)T_LEN);
            int ix = tp - 2;
            ix = (ix < 0) ? -ix : ix;
            ix = (ix > N_REFL) ? (2 * N_REFL - ix) : ix;
            s5[dt] = ix - mbase;
        }
        const int sC = s5[2];
        for (int i = 0; i < 8; ++i) {
            int o = 2 * wq + 8 * i;
            unsigned av[5];
            #pragma unroll
            for (int dt = 0; dt < 5; ++dt)
                av[dt] = *(const unsigned*)(phA + s5[dt] * POSTRIDE + o);
            unsigned l0a = *(const unsigned*)(phL0 + (sC    ) * POSTRIDE + o);
            unsigned l0b = *(const unsigned*)(phL0 + (sC + 1) * POSTRIDE + o);
            unsigned l1a = *(const unsigned*)(phL1 + (sC    ) * POSTRIDE + o);
            unsigned l1b = *(const unsigned*)(phL1 + (sC + 1) * POSTRIDE + o);

            float xm_l = bflo(av[2]), xm_h = bfhi(av[2]);
            float um_l = -1e30f, um_h = -1e30f;
            #pragma unroll
            for (int dt = 0; dt < 5; ++dt) {
                um_l = fmaxf(um_l, in5[dt] ? bflo(av[dt]) : 0.f);
                um_h = fmaxf(um_h, in5[dt] ? bfhi(av[dt]) : 0.f);
            }
            float l0al = bflo(l0a), l0bl = bflo(l0b), l1al = bflo(l1a), l1bl = bflo(l1b);
            float l0ah = bfhi(l0a), l0bh = bfhi(l0b), l1ah = bfhi(l1a), l1bh = bfhi(l1b);

            float rl = 2.f * xm_l + um_l + (l0bl + l0al) + qgelu(l0bl - l0al)
                                         + (l1bl + l1al) + qgelu(l1bl - l1al);
            float rh = 2.f * xm_h + um_h + (l0bh + l0ah) + qgelu(l0bh - l0ah)
                                         + (l1bh + l1ah) + qgelu(l1bh - l1ah);
            outp[(size_t)(o    ) * T_LEN] = rl;
            outp[(size_t)(o + 1) * T_LEN] = rh;
        }
    }
}

extern "C" void kernel_launch(void* const* d_in, const int* in_sizes, int n_in,
                              void* d_out, int out_size, void* d_ws, size_t ws_size,
                              hipStream_t stream) {
    const float* x    = (const float*)d_in[0];
    const float* w    = (const float*)d_in[1];
    const float* bias = (const float*)d_in[2];
    float* out        = (float*)d_out;
    ushort_t* wbf     = (ushort_t*)d_ws;    // 13*128*64*2 = 212,992 B

    hipLaunchKernelGGL(convert_w_kernel, dim3(416), dim3(256), 0, stream, w, wbf);

    const size_t need = WS_XT_OFF + (size_t)32 * XT_R * 64 * 2;  // ~33.9 MB
    if (ws_size >= need) {
        ushort_t* xT = (ushort_t*)((char*)d_ws + WS_XT_OFF);
        hipLaunchKernelGGL(transpose_kernel, dim3(128, 16), dim3(256), 0, stream, x, xT);
        hipLaunchKernelGGL(fused_int_kernel, dim3(N_INT), dim3(256), 0, stream,
                           xT, wbf, bias, out);
        hipLaunchKernelGGL(fused_bnd_kernel, dim3(64), dim3(256), 0, stream,
                           xT, wbf, bias, out);
    } else {
        hipLaunchKernelGGL(fused_trconv_r3, dim3(16 * 2 * 128), dim3(256), 0, stream,
                           x, wbf, bias, out);
    }
}